// Round 2
// baseline (900.683 us; speedup 1.0000x reference)
//
#include <hip/hip_runtime.h>

// Fourier Neural Operator spectral block, B=2 H=1024 W=1024 C=32, M1=M2=32.
// Only 64 row-modes x 32 col-modes survive -> four small separable transforms
// instead of full FFTs:
//   A: T[b,h,k2,c]  = sum_w x[b,h,w,c] e^{-i 2pi k2 w/W}          (8.6 GF)
//   B: F[b,j,k2,c]  = sum_h T e^{-i 2pi k1(j) h/H};  F *= w0*w{1,2}/(HW)
//   C: g[b,h,k2,c]  = sum_j F e^{+i 2pi k1(j) h/H}
//   D: y[b,h,w,c]   = Re(g0) + 2 sum_{k2>=1} (gre cos - gim sin)  (8.6 GF)
// k1(j) = j for j<32, 960+j for j>=32 (i.e. 992..1023).

#define B_ 2
#define H_ 1024
#define W_ 1024
#define C_ 32
#define M1_ 32
#define M2_ 32
#define NK1_ 64
#define NORM_ (1.0f / 1048576.0f)

// ---------------------------------------------------------------- tables ----
__global__ __launch_bounds__(256) void k_tables(float2* __restrict__ tabW,
                                                float2* __restrict__ tabWT,
                                                float2* __restrict__ tabH,
                                                float2* __restrict__ tabHT) {
  int idx = blockIdx.x * 256 + threadIdx.x;
  if (idx < W_ * M2_) {
    int w = idx >> 5, k2 = idx & 31;
    int ph = (w * k2) & (W_ - 1);
    float a = (float)ph * (1.0f / 512.0f);  // angle / pi
    float c = cospif(a), s = sinpif(a);
    tabW[idx] = make_float2(c, s);
    tabWT[k2 * W_ + w] = make_float2(c, s);
  } else if (idx < W_ * M2_ + H_ * NK1_) {
    int r = idx - W_ * M2_;
    int h = r >> 6, j = r & 63;
    int k1 = (j < 32) ? j : (960 + j);
    int ph = (k1 * h) & (H_ - 1);
    float a = (float)ph * (1.0f / 512.0f);
    float c = cospif(a), s = sinpif(a);
    tabH[r] = make_float2(c, s);
    tabHT[j * H_ + h] = make_float2(c, s);
  }
}

// --------------------------------------------------------------- stage A ----
// grid = B*H blocks, 256 threads. Thread owns c-pair (cp) x k2-pair (kp).
__global__ __launch_bounds__(256) void k_stageA(const float* __restrict__ x,
                                                const float2* __restrict__ tabW,
                                                float2* __restrict__ T) {
  __shared__ float lx[128 * 32];    // 16 KB: x chunk [128 w][32 c]
  __shared__ float2 lt[128 * 32];   // 32 KB: table chunk [128 w][32 k2]
  const int bh = blockIdx.x;
  const int t = threadIdx.x;
  const int cp = t & 15, kp = t >> 4;
  const int c = cp * 2, k2 = kp * 2;
  const float* xrow = x + (size_t)bh * (W_ * C_);

  float a00r = 0.f, a00i = 0.f, a01r = 0.f, a01i = 0.f;
  float a10r = 0.f, a10i = 0.f, a11r = 0.f, a11i = 0.f;

  for (int ch = 0; ch < 8; ++ch) {
    const float4* xs = (const float4*)(xrow + ch * 128 * 32);
    float4* lx4 = (float4*)lx;
    for (int i = t; i < 1024; i += 256) lx4[i] = xs[i];
    const float4* ts = (const float4*)(tabW + ch * 128 * 32);
    float4* lt4 = (float4*)lt;
    for (int i = t; i < 2048; i += 256) lt4[i] = ts[i];
    __syncthreads();
#pragma unroll 4
    for (int w = 0; w < 128; ++w) {
      float2 xv = *(const float2*)&lx[w * 32 + c];
      float4 tb = *(const float4*)&lt[w * 32 + k2];  // {cos0,sin0,cos1,sin1}
      a00r += xv.x * tb.x; a00i -= xv.x * tb.y;
      a01r += xv.x * tb.z; a01i -= xv.x * tb.w;
      a10r += xv.y * tb.x; a10i -= xv.y * tb.y;
      a11r += xv.y * tb.z; a11i -= xv.y * tb.w;
    }
    __syncthreads();
  }
  // T layout [b*H+h][k2][c] float2
  *(float4*)&T[((size_t)bh * M2_ + k2) * C_ + c]       = make_float4(a00r, a00i, a10r, a10i);
  *(float4*)&T[((size_t)bh * M2_ + (k2 + 1)) * C_ + c] = make_float4(a01r, a01i, a11r, a11i);
}

// -------------------------------------------------------------- stage BC ----
// grid = B*M2*(C/2) = 1024 blocks. Block owns (b, k2, c-pair); does fwd-H,
// weight multiply, inv-H for its slice.
__global__ __launch_bounds__(256) void k_stageBC(
    const float2* __restrict__ T, const float2* __restrict__ tabH,
    const float2* __restrict__ tabHT,
    const float* __restrict__ w0_re, const float* __restrict__ w0_im,
    const float* __restrict__ w1_re, const float* __restrict__ w1_im,
    const float* __restrict__ w2_re, const float* __restrict__ w2_im,
    float2* __restrict__ G) {
  __shared__ float4 Tl[1028];    // [h + (h>>8)] padded to dodge q-stride conflicts
  __shared__ float4 part[256];   // per-thread partial F
  __shared__ float4 FwL[64];     // weighted modes

  const int bid = blockIdx.x;
  const int b = bid >> 9;
  const int r = bid & 511;
  const int k2 = r >> 4;
  const int c0 = (r & 15) * 2;
  const int t = threadIdx.x;

  for (int i = t; i < 1024; i += 256) {
    const float2* src = &T[(((size_t)b * H_ + i) * M2_ + k2) * C_ + c0];
    Tl[i + (i >> 8)] = *(const float4*)src;
  }
  __syncthreads();

  // phase B: F[j] = sum_h T[h] * conj-exp.  thread = (j = t>>2, quarter q = t&3)
  const int j = t >> 2, q = t & 3;
  float4 F = make_float4(0.f, 0.f, 0.f, 0.f);
#pragma unroll 4
  for (int hh = 0; hh < 256; ++hh) {
    int h = q * 256 + hh;
    float4 tv = Tl[h + (h >> 8)];
    float2 e = tabH[h * NK1_ + j];  // {cos, sin} of +theta
    F.x += tv.x * e.x + tv.y * e.y;
    F.y += tv.y * e.x - tv.x * e.y;
    F.z += tv.z * e.x + tv.w * e.y;
    F.w += tv.w * e.x - tv.z * e.y;
  }
  part[t] = F;
  __syncthreads();

  if (t < 64) {
    float4 s0 = part[t * 4 + 0], s1 = part[t * 4 + 1];
    float4 s2 = part[t * 4 + 2], s3 = part[t * 4 + 3];
    float4 s = make_float4(s0.x + s1.x + s2.x + s3.x, s0.y + s1.y + s2.y + s3.y,
                           s0.z + s1.z + s2.z + s3.z, s0.w + s1.w + s2.w + s3.w);
    int jj = (t < 32) ? t : (t - 32);
    const float* mre = (t < 32) ? w1_re : w2_re;
    const float* mim = (t < 32) ? w1_im : w2_im;
    float4 fw;
    {
      int c = c0;
      float wr = w0_re[c], wi = w0_im[c];
      float mr = mre[(c * M1_ + jj) * M2_ + k2];
      float mi = mim[(c * M1_ + jj) * M2_ + k2];
      float pr = (wr * mr - wi * mi) * NORM_;
      float pi = (wr * mi + wi * mr) * NORM_;
      fw.x = s.x * pr - s.y * pi;
      fw.y = s.x * pi + s.y * pr;
    }
    {
      int c = c0 + 1;
      float wr = w0_re[c], wi = w0_im[c];
      float mr = mre[(c * M1_ + jj) * M2_ + k2];
      float mi = mim[(c * M1_ + jj) * M2_ + k2];
      float pr = (wr * mr - wi * mi) * NORM_;
      float pi = (wr * mi + wi * mr) * NORM_;
      fw.z = s.z * pr - s.w * pi;
      fw.w = s.z * pi + s.w * pr;
    }
    FwL[t] = fw;
  }
  __syncthreads();

  // phase C: g[h'] = sum_j Fw[j] * exp(+i theta)
  for (int hq = 0; hq < 4; ++hq) {
    int h = hq * 256 + t;
    float gx = 0.f, gy = 0.f, gz = 0.f, gw = 0.f;
#pragma unroll 4
    for (int jx = 0; jx < 64; ++jx) {
      float4 f = FwL[jx];
      float2 e = tabHT[jx * H_ + h];
      gx += f.x * e.x - f.y * e.y;
      gy += f.x * e.y + f.y * e.x;
      gz += f.z * e.x - f.w * e.y;
      gw += f.z * e.y + f.w * e.x;
    }
    *(float4*)&G[(((size_t)b * H_ + h) * M2_ + k2) * C_ + c0] =
        make_float4(gx, gy, gz, gw);
  }
}

// --------------------------------------------------------------- stage D ----
// grid = B*H blocks. Thread owns (cp = c/2, wg) -> 4 w x 2 c outputs per chunk.
__global__ __launch_bounds__(256) void k_stageD(const float2* __restrict__ G,
                                                const float2* __restrict__ tabWT,
                                                float* __restrict__ y) {
  __shared__ float4 coefL[512];   // [k2][cp] = {A(c0), B(c0), A(c1), B(c1)}
  __shared__ float2 ltw[2048];    // [k2][64 w] chunk of tabWT

  const int bh = blockIdx.x;
  const int t = threadIdx.x;
  const float4* gsl = (const float4*)(G + (size_t)bh * (M2_ * C_));
  for (int i = t; i < 512; i += 256) {
    float4 v = gsl[i];
    int k2 = i >> 4;
    float4 cf = (k2 == 0) ? make_float4(v.x, 0.f, v.z, 0.f)
                          : make_float4(2.f * v.x, -2.f * v.y, 2.f * v.z, -2.f * v.w);
    coefL[i] = cf;
  }

  const int cp = t & 15, wg = t >> 4;
  const int c = cp * 2;
  float* yrow = y + (size_t)bh * (W_ * C_);

  for (int wc = 0; wc < 16; ++wc) {
    const int w0 = wc * 64;
    __syncthreads();  // also covers coefL on first iteration
    const float4* tws = (const float4*)tabWT;
    float4* lt4 = (float4*)ltw;
    for (int i = t; i < 1024; i += 256) {
      int k2 = i >> 5, wl2 = i & 31;
      lt4[i] = tws[k2 * 512 + (w0 >> 1) + wl2];
    }
    __syncthreads();

    float a0c0 = 0.f, a0c1 = 0.f, a1c0 = 0.f, a1c1 = 0.f;
    float a2c0 = 0.f, a2c1 = 0.f, a3c0 = 0.f, a3c1 = 0.f;
#pragma unroll 4
    for (int k2 = 0; k2 < 32; ++k2) {
      float4 ta = *(const float4*)&ltw[k2 * 64 + wg * 4];      // w0,w1 {c,s}
      float4 tb = *(const float4*)&ltw[k2 * 64 + wg * 4 + 2];  // w2,w3 {c,s}
      float4 cf = coefL[k2 * 16 + cp];
      a0c0 += cf.x * ta.x + cf.y * ta.y; a0c1 += cf.z * ta.x + cf.w * ta.y;
      a1c0 += cf.x * ta.z + cf.y * ta.w; a1c1 += cf.z * ta.z + cf.w * ta.w;
      a2c0 += cf.x * tb.x + cf.y * tb.y; a2c1 += cf.z * tb.x + cf.w * tb.y;
      a3c0 += cf.x * tb.z + cf.y * tb.w; a3c1 += cf.z * tb.z + cf.w * tb.w;
    }
    int wbase = w0 + wg * 4;
    *(float2*)&yrow[(wbase + 0) * C_ + c] = make_float2(a0c0, a0c1);
    *(float2*)&yrow[(wbase + 1) * C_ + c] = make_float2(a1c0, a1c1);
    *(float2*)&yrow[(wbase + 2) * C_ + c] = make_float2(a2c0, a2c1);
    *(float2*)&yrow[(wbase + 3) * C_ + c] = make_float2(a3c0, a3c1);
  }
}

// ---------------------------------------------------------------- launch ----
extern "C" void kernel_launch(void* const* d_in, const int* in_sizes, int n_in,
                              void* d_out, int out_size, void* d_ws, size_t ws_size,
                              hipStream_t stream) {
  const float* x = (const float*)d_in[0];
  const float* w0_re = (const float*)d_in[1];
  const float* w0_im = (const float*)d_in[2];
  const float* w1_re = (const float*)d_in[3];
  const float* w1_im = (const float*)d_in[4];
  const float* w2_re = (const float*)d_in[5];
  const float* w2_im = (const float*)d_in[6];
  float* y = (float*)d_out;

  // ws layout (float2 units): tabW 32768 | tabWT 32768 | tabH 65536 |
  // tabHT 65536 | T 2097152 | G 2097152   -> ~35 MB total
  float2* tabW = (float2*)d_ws;
  float2* tabWT = tabW + 32768;
  float2* tabH = tabWT + 32768;
  float2* tabHT = tabH + 65536;
  float2* T = tabHT + 65536;
  float2* G = T + 2097152;

  hipLaunchKernelGGL(k_tables, dim3(384), dim3(256), 0, stream,
                     tabW, tabWT, tabH, tabHT);
  hipLaunchKernelGGL(k_stageA, dim3(B_ * H_), dim3(256), 0, stream, x, tabW, T);
  hipLaunchKernelGGL(k_stageBC, dim3(B_ * M2_ * (C_ / 2)), dim3(256), 0, stream,
                     T, tabH, tabHT, w0_re, w0_im, w1_re, w1_im, w2_re, w2_im, G);
  hipLaunchKernelGGL(k_stageD, dim3(B_ * H_), dim3(256), 0, stream, G, tabWT, y);
}

// Round 3
// 880.476 us; speedup vs baseline: 1.0229x; 1.0229x over previous
//
#include <hip/hip_runtime.h>

// Fourier Neural Operator spectral block, B=2 H=1024 W=1024 C=32, M1=M2=32.
//   A: T[b,h,k2,c]  = sum_w x[b,h,w,c] e^{-i 2pi k2 w/W}          (8.6 GF)
//   B: F[b,j,k2,c]  = sum_h T e^{-i 2pi k1(j) h/H};  F *= w0*w{1,2}/(HW)
//   C: g[b,h,k2,c]  = sum_j F e^{+i 2pi k1(j) h/H}
//   D: y[b,h,w,c]   = Re(g0) + 2 sum_{k2>=1} (gre cos - gim sin)  (8.6 GF)
// k1(j) = j for j<32, 960+j for j>=32.

#define B_ 2
#define H_ 1024
#define W_ 1024
#define C_ 32
#define M1_ 32
#define M2_ 32
#define NK1_ 64
#define NORM_ (1.0f / 1048576.0f)

// ---------------------------------------------------------------- tables ----
__global__ __launch_bounds__(256) void k_tables(float2* __restrict__ tabW,
                                                float2* __restrict__ tabWT,
                                                float2* __restrict__ tabH,
                                                float2* __restrict__ tabHT) {
  int idx = blockIdx.x * 256 + threadIdx.x;
  if (idx < W_ * M2_) {
    int w = idx >> 5, k2 = idx & 31;
    int ph = (w * k2) & (W_ - 1);
    float a = (float)ph * (1.0f / 512.0f);  // angle / pi
    float c = cospif(a), s = sinpif(a);
    tabW[idx] = make_float2(c, s);
    tabWT[k2 * W_ + w] = make_float2(c, s);
  } else if (idx < W_ * M2_ + H_ * NK1_) {
    int r = idx - W_ * M2_;
    int h = r >> 6, j = r & 63;
    int k1 = (j < 32) ? j : (960 + j);
    int ph = (k1 * h) & (H_ - 1);
    float a = (float)ph * (1.0f / 512.0f);
    float c = cospif(a), s = sinpif(a);
    tabH[r] = make_float2(c, s);
    tabHT[j * H_ + h] = make_float2(c, s);
  }
}

// --------------------------------------------------------------- stage A ----
// grid = B*H. Thread = (cg: 4 c, kg: 2 k2, half: w-half). 16 FMA / 32B LDS.
__global__ __launch_bounds__(256) void k_stageA(const float* __restrict__ x,
                                                const float2* __restrict__ tabW,
                                                float2* __restrict__ T) {
  __shared__ float lx[64 * 32];    // 8 KB  [w][c]
  __shared__ float2 lt[64 * 32];   // 16 KB [w][k2] {cos,sin}
  const int bh = blockIdx.x;
  const int t = threadIdx.x;
  const int cg = t & 7;
  const int kg = (t >> 3) & 15;
  const int half = t >> 7;
  const int c0 = cg * 4;

  float a[16];  // [kk(2)][re/im(2)][c(4)]
#pragma unroll
  for (int i = 0; i < 16; ++i) a[i] = 0.f;

  const float4* xg = (const float4*)(x + (size_t)bh * (W_ * C_));
  const float4* tg = (const float4*)tabW;
  float4* lx4 = (float4*)lx;
  float4* lt4 = (float4*)lt;

  for (int ch = 0; ch < 16; ++ch) {
    lx4[t] = xg[ch * 512 + t];
    lx4[t + 256] = xg[ch * 512 + t + 256];
#pragma unroll
    for (int i = 0; i < 4; ++i) lt4[t + i * 256] = tg[ch * 1024 + t + i * 256];
    __syncthreads();
#pragma unroll 4
    for (int wl = 0; wl < 32; ++wl) {
      const int w = half * 32 + wl;
      const float4 xv = *(const float4*)&lx[w * 32 + c0];
      const float4 e = *(const float4*)&lt[w * 32 + kg * 2];  // {c0,s0,c1,s1}
      a[0] += xv.x * e.x;  a[4] -= xv.x * e.y;
      a[1] += xv.y * e.x;  a[5] -= xv.y * e.y;
      a[2] += xv.z * e.x;  a[6] -= xv.z * e.y;
      a[3] += xv.w * e.x;  a[7] -= xv.w * e.y;
      a[8] += xv.x * e.z;  a[12] -= xv.x * e.w;
      a[9] += xv.y * e.z;  a[13] -= xv.y * e.w;
      a[10] += xv.z * e.z; a[14] -= xv.z * e.w;
      a[11] += xv.w * e.z; a[15] -= xv.w * e.w;
    }
    __syncthreads();
  }
  // cross-half reduction: half-1 publishes into lt, half-0 accumulates+stores.
  float4* red = (float4*)lt;
  if (half) {
#pragma unroll
    for (int r = 0; r < 4; ++r)
      red[(t - 128) * 4 + r] =
          make_float4(a[r * 4], a[r * 4 + 1], a[r * 4 + 2], a[r * 4 + 3]);
  }
  __syncthreads();
  if (!half) {
#pragma unroll
    for (int r = 0; r < 4; ++r) {
      float4 v = red[t * 4 + r];
      a[r * 4] += v.x; a[r * 4 + 1] += v.y;
      a[r * 4 + 2] += v.z; a[r * 4 + 3] += v.w;
    }
#pragma unroll
    for (int kk = 0; kk < 2; ++kk) {
      float2* dst = &T[((size_t)bh * M2_ + (kg * 2 + kk)) * C_ + c0];
      *(float4*)dst = make_float4(a[kk * 8 + 0], a[kk * 8 + 4],
                                  a[kk * 8 + 1], a[kk * 8 + 5]);
      *(float4*)(dst + 2) = make_float4(a[kk * 8 + 2], a[kk * 8 + 6],
                                        a[kk * 8 + 3], a[kk * 8 + 7]);
    }
  }
}

// -------------------------------------------------------------- stage BC ----
// grid = B*M2*(C/2) = 1024 blocks. Block owns (b, k2, c-pair); fwd-H,
// weight multiply, inv-H for its slice.  (unchanged this round)
__global__ __launch_bounds__(256) void k_stageBC(
    const float2* __restrict__ T, const float2* __restrict__ tabH,
    const float2* __restrict__ tabHT,
    const float* __restrict__ w0_re, const float* __restrict__ w0_im,
    const float* __restrict__ w1_re, const float* __restrict__ w1_im,
    const float* __restrict__ w2_re, const float* __restrict__ w2_im,
    float2* __restrict__ G) {
  __shared__ float4 Tl[1028];
  __shared__ float4 part[256];
  __shared__ float4 FwL[64];

  const int bid = blockIdx.x;
  const int b = bid >> 9;
  const int r = bid & 511;
  const int k2 = r >> 4;
  const int c0 = (r & 15) * 2;
  const int t = threadIdx.x;

  for (int i = t; i < 1024; i += 256) {
    const float2* src = &T[(((size_t)b * H_ + i) * M2_ + k2) * C_ + c0];
    Tl[i + (i >> 8)] = *(const float4*)src;
  }
  __syncthreads();

  const int j = t >> 2, q = t & 3;
  float4 F = make_float4(0.f, 0.f, 0.f, 0.f);
#pragma unroll 4
  for (int hh = 0; hh < 256; ++hh) {
    int h = q * 256 + hh;
    float4 tv = Tl[h + (h >> 8)];
    float2 e = tabH[h * NK1_ + j];
    F.x += tv.x * e.x + tv.y * e.y;
    F.y += tv.y * e.x - tv.x * e.y;
    F.z += tv.z * e.x + tv.w * e.y;
    F.w += tv.w * e.x - tv.z * e.y;
  }
  part[t] = F;
  __syncthreads();

  if (t < 64) {
    float4 s0 = part[t * 4 + 0], s1 = part[t * 4 + 1];
    float4 s2 = part[t * 4 + 2], s3 = part[t * 4 + 3];
    float4 s = make_float4(s0.x + s1.x + s2.x + s3.x, s0.y + s1.y + s2.y + s3.y,
                           s0.z + s1.z + s2.z + s3.z, s0.w + s1.w + s2.w + s3.w);
    int jj = (t < 32) ? t : (t - 32);
    const float* mre = (t < 32) ? w1_re : w2_re;
    const float* mim = (t < 32) ? w1_im : w2_im;
    float4 fw;
    {
      int c = c0;
      float wr = w0_re[c], wi = w0_im[c];
      float mr = mre[(c * M1_ + jj) * M2_ + k2];
      float mi = mim[(c * M1_ + jj) * M2_ + k2];
      float pr = (wr * mr - wi * mi) * NORM_;
      float pi = (wr * mi + wi * mr) * NORM_;
      fw.x = s.x * pr - s.y * pi;
      fw.y = s.x * pi + s.y * pr;
    }
    {
      int c = c0 + 1;
      float wr = w0_re[c], wi = w0_im[c];
      float mr = mre[(c * M1_ + jj) * M2_ + k2];
      float mi = mim[(c * M1_ + jj) * M2_ + k2];
      float pr = (wr * mr - wi * mi) * NORM_;
      float pi = (wr * mi + wi * mr) * NORM_;
      fw.z = s.z * pr - s.w * pi;
      fw.w = s.z * pi + s.w * pr;
    }
    FwL[t] = fw;
  }
  __syncthreads();

  for (int hq = 0; hq < 4; ++hq) {
    int h = hq * 256 + t;
    float gx = 0.f, gy = 0.f, gz = 0.f, gw = 0.f;
#pragma unroll 4
    for (int jx = 0; jx < 64; ++jx) {
      float4 f = FwL[jx];
      float2 e = tabHT[jx * H_ + h];
      gx += f.x * e.x - f.y * e.y;
      gy += f.x * e.y + f.y * e.x;
      gz += f.z * e.x - f.w * e.y;
      gw += f.z * e.y + f.w * e.x;
    }
    *(float4*)&G[(((size_t)b * H_ + h) * M2_ + k2) * C_ + c0] =
        make_float4(gx, gy, gz, gw);
  }
}

// --------------------------------------------------------------- stage D ----
// grid = B*H. Thread = (cg: 4 c, wg: 4 w). 32 FMA / 64B LDS per k2.
__global__ __launch_bounds__(256) void k_stageD(const float2* __restrict__ G,
                                                const float2* __restrict__ tabWT,
                                                float* __restrict__ y) {
  __shared__ float2 coefL[32 * 32];   // 8 KB  [k2][c] = {A,B}
  __shared__ float2 ltw[32 * 128];    // 32 KB [k2][wl] = {cos,sin}
  const int bh = blockIdx.x;
  const int t = threadIdx.x;
  const int cg = t & 7, wg = t >> 3;
  const int c0 = cg * 4;

  {
    const float4* gsl = (const float4*)(G + (size_t)bh * (M2_ * C_));
    float4* cf4 = (float4*)coefL;
#pragma unroll
    for (int j = 0; j < 4; ++j) {
      int i = t + j * 256;
      float4 v = gsl[i];
      int k2 = i >> 4;
      cf4[i] = (k2 == 0) ? make_float4(v.x, 0.f, v.z, 0.f)
                         : make_float4(2.f * v.x, -2.f * v.y,
                                       2.f * v.z, -2.f * v.w);
    }
  }
  const float4* twg = (const float4*)tabWT;
  float4* lt4 = (float4*)ltw;
  float* yrow = y + (size_t)bh * (W_ * C_);

  for (int ch = 0; ch < 8; ++ch) {
    const int w0 = ch * 128;
    __syncthreads();   // first iter also covers coefL writes
#pragma unroll
    for (int j = 0; j < 8; ++j) {
      int i = t + j * 256;  // k2 = i>>6, wl2 = i&63
      lt4[i] = twg[(i >> 6) * 512 + (w0 >> 1) + (i & 63)];
    }
    __syncthreads();

    float a[16];  // [c(4)][w(4)]
#pragma unroll
    for (int i = 0; i < 16; ++i) a[i] = 0.f;
#pragma unroll 4
    for (int k2 = 0; k2 < 32; ++k2) {
      const float4 cf0 = *(const float4*)&coefL[k2 * 32 + c0];      // A0,B0,A1,B1
      const float4 cf1 = *(const float4*)&coefL[k2 * 32 + c0 + 2];  // A2,B2,A3,B3
      const float4 e0 = *(const float4*)&ltw[k2 * 128 + wg * 4];    // c0,s0,c1,s1
      const float4 e1 = *(const float4*)&ltw[k2 * 128 + wg * 4 + 2];
      a[0]  += cf0.x * e0.x + cf0.y * e0.y;
      a[1]  += cf0.x * e0.z + cf0.y * e0.w;
      a[2]  += cf0.x * e1.x + cf0.y * e1.y;
      a[3]  += cf0.x * e1.z + cf0.y * e1.w;
      a[4]  += cf0.z * e0.x + cf0.w * e0.y;
      a[5]  += cf0.z * e0.z + cf0.w * e0.w;
      a[6]  += cf0.z * e1.x + cf0.w * e1.y;
      a[7]  += cf0.z * e1.z + cf0.w * e1.w;
      a[8]  += cf1.x * e0.x + cf1.y * e0.y;
      a[9]  += cf1.x * e0.z + cf1.y * e0.w;
      a[10] += cf1.x * e1.x + cf1.y * e1.y;
      a[11] += cf1.x * e1.z + cf1.y * e1.w;
      a[12] += cf1.z * e0.x + cf1.w * e0.y;
      a[13] += cf1.z * e0.z + cf1.w * e0.w;
      a[14] += cf1.z * e1.x + cf1.w * e1.y;
      a[15] += cf1.z * e1.z + cf1.w * e1.w;
    }
#pragma unroll
    for (int wi = 0; wi < 4; ++wi) {
      *(float4*)&yrow[(w0 + wg * 4 + wi) * C_ + c0] =
          make_float4(a[wi], a[4 + wi], a[8 + wi], a[12 + wi]);
    }
  }
}

// ---------------------------------------------------------------- launch ----
extern "C" void kernel_launch(void* const* d_in, const int* in_sizes, int n_in,
                              void* d_out, int out_size, void* d_ws, size_t ws_size,
                              hipStream_t stream) {
  const float* x = (const float*)d_in[0];
  const float* w0_re = (const float*)d_in[1];
  const float* w0_im = (const float*)d_in[2];
  const float* w1_re = (const float*)d_in[3];
  const float* w1_im = (const float*)d_in[4];
  const float* w2_re = (const float*)d_in[5];
  const float* w2_im = (const float*)d_in[6];
  float* y = (float*)d_out;

  float2* tabW = (float2*)d_ws;
  float2* tabWT = tabW + 32768;
  float2* tabH = tabWT + 32768;
  float2* tabHT = tabH + 65536;
  float2* T = tabHT + 65536;
  float2* G = T + 2097152;

  hipLaunchKernelGGL(k_tables, dim3(384), dim3(256), 0, stream,
                     tabW, tabWT, tabH, tabHT);
  hipLaunchKernelGGL(k_stageA, dim3(B_ * H_), dim3(256), 0, stream, x, tabW, T);
  hipLaunchKernelGGL(k_stageBC, dim3(B_ * M2_ * (C_ / 2)), dim3(256), 0, stream,
                     T, tabH, tabHT, w0_re, w0_im, w1_re, w1_im, w2_re, w2_im, G);
  hipLaunchKernelGGL(k_stageD, dim3(B_ * H_), dim3(256), 0, stream, G, tabWT, y);
}